// Round 7
// baseline (745.693 us; speedup 1.0000x reference)
//
#include <hip/hip_runtime.h>

#define NEG_SLOPE 0.2f
#define LN_EPS 1e-5f

typedef __attribute__((ext_vector_type(8))) short bf16x8;
typedef __attribute__((ext_vector_type(4))) float f32x4;

__device__ __forceinline__ ushort f2bf(float f) {  // round-to-nearest-even
    uint u = __float_as_uint(f);
    u += 0x7fffu + ((u >> 16) & 1u);
    return (ushort)(u >> 16);
}

// ---------------------------------------------------------------- prep kernels

__global__ void count_kernel(const int* __restrict__ dst0, const float* __restrict__ eattr,
                             int* __restrict__ cnt, float* __restrict__ easum, int E_) {
    int e = blockIdx.x * 256 + threadIdx.x;
    if (e >= E_) return;
    int d = dst0[e];
    atomicAdd(&cnt[d], 1);
    atomicAdd(&easum[d], eattr[e]);
}

// scan over (cnt+1) with fused self-loop emission
__global__ void scan_kernel(const int* __restrict__ cnt, const float* __restrict__ easum,
                            int* __restrict__ rowstart, int2* __restrict__ csr,
                            int* __restrict__ cursor, int N_) {
    __shared__ int lds[1024];
    int t = threadIdx.x;
    int chunk = (N_ + 1023) >> 10;
    int begin = t * chunk;
    int end = begin + chunk; if (end > N_) end = N_; if (begin > N_) begin = N_;
    int s = 0;
    for (int i = begin; i < end; ++i) s += cnt[i] + 1;
    lds[t] = s;
    __syncthreads();
    for (int off = 1; off < 1024; off <<= 1) {
        int v = (t >= off) ? lds[t - off] : 0;
        __syncthreads();
        lds[t] += v;
        __syncthreads();
    }
    int run = lds[t] - s;  // exclusive base
    for (int i = begin; i < end; ++i) {
        rowstart[i] = run;
        int c = cnt[i];
        csr[run] = make_int2(i, __float_as_int(easum[i] / (float)(c > 1 ? c : 1)));
        cursor[i] = run + 1;
        run += c + 1;
    }
    if (t == 1023) rowstart[N_] = lds[1023];
}

__global__ void scatter_kernel(const int* __restrict__ src0, const int* __restrict__ dst0,
                               const float* __restrict__ eattr, int* __restrict__ cursor,
                               int2* __restrict__ csr, int E_) {
    int e = blockIdx.x * 256 + threadIdx.x;
    if (e >= E_) return;
    int d = dst0[e];
    int p = atomicAdd(&cursor[d], 1);
    csr[p] = make_int2(src0[e], __float_as_int(eattr[e]));
}

// pack weights into bf16 MFMA B-fragment order, + convert x to bf16.
// wpack: [0,98304) Wl0..2,Wr0..2 (128x128); [98304,102400) W_in (32x128);
// [102400,110592) Wn (128x64).
__global__ void pack_cvt_kernel(const float* __restrict__ Wl, const float* __restrict__ Wr,
                                const float* __restrict__ Win, const float* __restrict__ Wn,
                                const float* __restrict__ x, ushort* __restrict__ wpack,
                                ushort* __restrict__ xb, int nx4) {
    int idx = blockIdx.x * 256 + threadIdx.x;
    if (idx < 110592) {
        const float* src; int Ncol, rel;
        if (idx < 98304) {
            int m = idx >> 14; rel = idx & 16383;
            src = m < 3 ? Wl + m * 16384 : Wr + (m - 3) * 16384;
            Ncol = 128;
        } else if (idx < 102400) {
            rel = idx - 98304; src = Win; Ncol = 128;
        } else {
            rel = idx - 102400; src = Wn; Ncol = 64;
        }
        int j = rel & 7, lane = (rel >> 3) & 63, rest = rel >> 9;
        int nc16 = Ncol >> 4;
        int c = rest % nc16, ks = rest / nc16;
        int k = ks * 32 + ((lane >> 4) << 3) + j;
        int col = c * 16 + (lane & 15);
        wpack[idx] = f2bf(src[k * Ncol + col]);
    } else {
        int i = idx - 110592;
        if (i < nx4) {
            float4 v = *(const float4*)(x + (size_t)i * 4);
            ushort4 o;
            o.x = f2bf(v.x); o.y = f2bf(v.y); o.z = f2bf(v.z); o.w = f2bf(v.w);
            *(ushort4*)(xb + (size_t)i * 4) = o;
        }
    }
}

// ---------------------------------------------------------------- MFMA GEMMs
// A-frag: row = lane&15, k = (lane>>4)*8 + j. D-frag: col = lane&15, row = (lane>>4)*4 + reg.

__global__ __launch_bounds__(256) void mfma_inproj(
    const ushort* __restrict__ x_bf, const ushort* __restrict__ Wp,
    const float* __restrict__ b_in, float* __restrict__ h, ushort* __restrict__ h_bf, int N_) {
    int wave = threadIdx.x >> 6, lane = threadIdx.x & 63;
    int row0 = blockIdx.x * 64 + wave * 16;
    int arow = row0 + (lane & 15); if (arow >= N_) arow = N_ - 1;
    int koff = (lane >> 4) * 8;
    bf16x8 a = *(const bf16x8*)(x_bf + (size_t)arow * 32 + koff);
    f32x4 acc[8];
#pragma unroll
    for (int c = 0; c < 8; ++c) acc[c] = {0.f, 0.f, 0.f, 0.f};
#pragma unroll
    for (int c = 0; c < 8; ++c) {
        bf16x8 b = *(const bf16x8*)(Wp + ((size_t)c * 64 + lane) * 8);
        acc[c] = __builtin_amdgcn_mfma_f32_16x16x32_bf16(a, b, acc[c], 0, 0, 0);
    }
    int srow = row0 + (lane >> 4) * 4;
    int scol = lane & 15;
#pragma unroll
    for (int c = 0; c < 8; ++c) {
        float bi = b_in[c * 16 + scol];
#pragma unroll
        for (int r = 0; r < 4; ++r) {
            int row = srow + r;
            if (row < N_) {
                float v = acc[c][r] + bi;
                h[(size_t)row * 128 + c * 16 + scol] = v;
                h_bf[(size_t)row * 128 + c * 16 + scol] = f2bf(v);
            }
        }
    }
}

// layer proj: 128 rows/block, wave = 32 rows (2 A-frags per B-frag load)
__global__ __launch_bounds__(256, 1) void mfma_proj(
    const ushort* __restrict__ h_bf, const ushort* __restrict__ Wlp,
    const ushort* __restrict__ Wrp, const float* __restrict__ bl, const float* __restrict__ br,
    ushort* __restrict__ xl, ushort* __restrict__ xr, int N_) {
    int wave = threadIdx.x >> 6, lane = threadIdx.x & 63;
    int row0 = blockIdx.x * 128 + wave * 32;
    int ar0 = row0 + (lane & 15); if (ar0 >= N_) ar0 = N_ - 1;
    int ar1 = row0 + 16 + (lane & 15); if (ar1 >= N_) ar1 = N_ - 1;
    int koff = (lane >> 4) * 8;
    f32x4 accL[2][8], accR[2][8];
#pragma unroll
    for (int g = 0; g < 2; ++g)
#pragma unroll
        for (int c = 0; c < 8; ++c) { accL[g][c] = {0.f, 0.f, 0.f, 0.f}; accR[g][c] = {0.f, 0.f, 0.f, 0.f}; }
#pragma unroll
    for (int ks = 0; ks < 4; ++ks) {
        bf16x8 a0 = *(const bf16x8*)(h_bf + (size_t)ar0 * 128 + ks * 32 + koff);
        bf16x8 a1 = *(const bf16x8*)(h_bf + (size_t)ar1 * 128 + ks * 32 + koff);
        const ushort* wl = Wlp + ((size_t)ks * 8 * 64 + lane) * 8;
        const ushort* wr = Wrp + ((size_t)ks * 8 * 64 + lane) * 8;
#pragma unroll
        for (int c = 0; c < 8; ++c) {
            bf16x8 bL = *(const bf16x8*)(wl + c * 512);
            accL[0][c] = __builtin_amdgcn_mfma_f32_16x16x32_bf16(a0, bL, accL[0][c], 0, 0, 0);
            accL[1][c] = __builtin_amdgcn_mfma_f32_16x16x32_bf16(a1, bL, accL[1][c], 0, 0, 0);
            bf16x8 bR = *(const bf16x8*)(wr + c * 512);
            accR[0][c] = __builtin_amdgcn_mfma_f32_16x16x32_bf16(a0, bR, accR[0][c], 0, 0, 0);
            accR[1][c] = __builtin_amdgcn_mfma_f32_16x16x32_bf16(a1, bR, accR[1][c], 0, 0, 0);
        }
    }
    int scol = lane & 15;
#pragma unroll
    for (int g = 0; g < 2; ++g) {
        int srow = row0 + g * 16 + (lane >> 4) * 4;
#pragma unroll
        for (int c = 0; c < 8; ++c) {
            float bLv = bl[c * 16 + scol];
            float bRv = br[c * 16 + scol];
#pragma unroll
            for (int r = 0; r < 4; ++r) {
                int row = srow + r;
                if (row < N_) {
                    xl[(size_t)row * 128 + c * 16 + scol] = f2bf(accL[g][c][r] + bLv);
                    xr[(size_t)row * 128 + c * 16 + scol] = f2bf(accR[g][c][r] + bRv);
                }
            }
        }
    }
}

__global__ __launch_bounds__(256) void mfma_nodeemb(
    const ushort* __restrict__ h_bf, const ushort* __restrict__ Wp,
    const float* __restrict__ bn, float* __restrict__ node_emb, int N_) {
    int wave = threadIdx.x >> 6, lane = threadIdx.x & 63;
    int row0 = blockIdx.x * 64 + wave * 16;
    int arow = row0 + (lane & 15); if (arow >= N_) arow = N_ - 1;
    int koff = (lane >> 4) * 8;
    f32x4 acc[4];
#pragma unroll
    for (int c = 0; c < 4; ++c) acc[c] = {0.f, 0.f, 0.f, 0.f};
#pragma unroll
    for (int ks = 0; ks < 4; ++ks) {
        bf16x8 a = *(const bf16x8*)(h_bf + (size_t)arow * 128 + ks * 32 + koff);
#pragma unroll
        for (int c = 0; c < 4; ++c) {
            bf16x8 b = *(const bf16x8*)(Wp + ((size_t)(ks * 4 + c) * 64 + lane) * 8);
            acc[c] = __builtin_amdgcn_mfma_f32_16x16x32_bf16(a, b, acc[c], 0, 0, 0);
        }
    }
    int srow = row0 + (lane >> 4) * 4;
    int scol = lane & 15;
#pragma unroll
    for (int c = 0; c < 4; ++c) {
        float bi = bn[c * 16 + scol];
#pragma unroll
        for (int r = 0; r < 4; ++r) {
            int row = srow + r;
            if (row < N_) node_emb[(size_t)row * 64 + c * 16 + scol] = acc[c][r] + bi;
        }
    }
}

// ---------------------------------------------------------------- per-node aggregation
// DPP 16-lane head reduce (full-rate VALU).

__device__ __forceinline__ float head16_sum(float x) {
    int v;
    v = __builtin_amdgcn_update_dpp(0, __float_as_int(x), 0xB1, 0xF, 0xF, true);
    x += __int_as_float(v);
    v = __builtin_amdgcn_update_dpp(0, __float_as_int(x), 0x4E, 0xF, 0xF, true);
    x += __int_as_float(v);
    v = __builtin_amdgcn_update_dpp(0, __float_as_int(x), 0x141, 0xF, 0xF, true);
    x += __int_as_float(v);
    v = __builtin_amdgcn_update_dpp(0, __float_as_int(x), 0x140, 0xF, 0xF, true);
    x += __int_as_float(v);
    return x;
}

// no-max softmax (alpha is O(1) for this model; clamp +-60 guards exp).
// exact vs reference up to fp rounding: softmax is shift-invariant.
__device__ __forceinline__ void edge_step(const uint* __restrict__ xlw,
                                          const int2* __restrict__ csr, int p, uint lane,
                                          float we2x, float we2y, float xr2x, float xr2y,
                                          float atx, float aty,
                                          float& d, float& ax, float& ay) {
    int2 e = csr[p];
    uint off = ((uint)e.x << 6) + lane;
    uint va = xlw[off];
    float xax = __uint_as_float(va << 16);
    float xay = __uint_as_float(va & 0xffff0000u);
    float ea = __int_as_float(e.y);
    float mx = xax + fmaf(ea, we2x, xr2x);
    float my = xay + fmaf(ea, we2y, xr2y);
    mx = fmaxf(mx, NEG_SLOPE * mx);
    my = fmaxf(my, NEG_SLOPE * my);
    float al = head16_sum(fmaf(my, aty, mx * atx));
    al = fminf(fmaxf(al, -60.f), 60.f);
    float pe = __expf(al);
    d += pe;
    ax = fmaf(pe, xax, ax);
    ay = fmaf(pe, xay, ay);
}

__global__ __launch_bounds__(256) void aggregate_kernel(
    float* __restrict__ h, const ushort* __restrict__ xl, const ushort* __restrict__ xr,
    const int* __restrict__ rowstart, const int2* __restrict__ csr,
    const float* __restrict__ We, const float* __restrict__ att, const float* __restrict__ bc,
    const float* __restrict__ ln_g, const float* __restrict__ ln_b,
    ushort* __restrict__ h_bf, float* __restrict__ h_out, int N_) {
    int wave = threadIdx.x >> 6;
    uint lane = threadIdx.x & 63;
    int n = blockIdx.x * 4 + wave;
    if (n >= N_) return;
    int c0 = lane * 2;
    int head = lane >> 4;
    const uint* xlw = (const uint*)xl;
    uint vr = *(const uint*)(xr + (size_t)n * 128 + c0);
    float xr2x = __uint_as_float(vr << 16);
    float xr2y = __uint_as_float(vr & 0xffff0000u);
    float2 we2 = *(const float2*)(We + c0);
    float2 at2 = *(const float2*)(att + head * 32 + (c0 & 31));
    int rs = rowstart[n], re = rowstart[n + 1];
    float d0 = 0.f, ax0 = 0.f, ay0 = 0.f;
    float d1 = 0.f, ax1 = 0.f, ay1 = 0.f;
    float d2 = 0.f, ax2 = 0.f, ay2 = 0.f;
    float d3 = 0.f, ax3 = 0.f, ay3 = 0.f;
    int p = rs;
    for (; p + 4 <= re; p += 4) {
        edge_step(xlw, csr, p,     lane, we2.x, we2.y, xr2x, xr2y, at2.x, at2.y, d0, ax0, ay0);
        edge_step(xlw, csr, p + 1, lane, we2.x, we2.y, xr2x, xr2y, at2.x, at2.y, d1, ax1, ay1);
        edge_step(xlw, csr, p + 2, lane, we2.x, we2.y, xr2x, xr2y, at2.x, at2.y, d2, ax2, ay2);
        edge_step(xlw, csr, p + 3, lane, we2.x, we2.y, xr2x, xr2y, at2.x, at2.y, d3, ax3, ay3);
    }
    for (; p < re; ++p)
        edge_step(xlw, csr, p, lane, we2.x, we2.y, xr2x, xr2y, at2.x, at2.y, d0, ax0, ay0);
    float den = (d0 + d1) + (d2 + d3);
    float accx = (ax0 + ax1) + (ax2 + ax3);
    float accy = (ay0 + ay1) + (ay2 + ay3);
    float inv = 1.f / den;
    float2 bc2 = *(const float2*)(bc + c0);
    float ox = accx * inv + bc2.x;
    float oy = accy * inv + bc2.y;
    ox = ox > 0.f ? ox : (__expf(ox) - 1.f);  // elu
    oy = oy > 0.f ? oy : (__expf(oy) - 1.f);
    float2 h2 = *(const float2*)(h + (size_t)n * 128 + c0);
    float tx = h2.x + ox, ty = h2.y + oy;
    // one-pass LN: reduce sum and sumsq together
    float s1v = tx + ty;
    float s2v = tx * tx + ty * ty;
#pragma unroll
    for (int m = 1; m < 64; m <<= 1) {
        s1v += __shfl_xor(s1v, m);
        s2v += __shfl_xor(s2v, m);
    }
    float mu = s1v * (1.f / 128.f);
    float var = s2v * (1.f / 128.f) - mu * mu;
    float rstd = rsqrtf(var + LN_EPS);
    float2 g2 = *(const float2*)(ln_g + c0);
    float2 b2 = *(const float2*)(ln_b + c0);
    float2 hn;
    hn.x = (tx - mu) * rstd * g2.x + b2.x;
    hn.y = (ty - mu) * rstd * g2.y + b2.y;
    *(float2*)(h + (size_t)n * 128 + c0) = hn;
    uint packed = (uint)f2bf(hn.x) | ((uint)f2bf(hn.y) << 16);
    *(uint*)(h_bf + (size_t)n * 128 + c0) = packed;
    if (h_out) *(float2*)(h_out + (size_t)n * 128 + c0) = hn;
}

// ---------------------------------------------------------------- outputs

__global__ __launch_bounds__(256) void batch_kernel(
    const float* __restrict__ h, const int* __restrict__ batch,
    float* __restrict__ gsum, float* __restrict__ gcnt, int N_, int chunk) {
    int wave_id = (blockIdx.x * 256 + threadIdx.x) >> 6;
    int lane = threadIdx.x & 63;
    int w0 = wave_id * chunk;
    if (w0 >= N_) return;
    int w1 = w0 + chunk; if (w1 > N_) w1 = N_;
    int c0 = lane * 2;
    int cur_b = batch[w0];
    float accx = 0.f, accy = 0.f, cntf = 0.f;
    for (int n = w0; n < w1; ++n) {
        float2 h2 = *(const float2*)(h + (size_t)n * 128 + c0);
        int b = batch[n];
        if (b != cur_b) {
            atomicAdd(&gsum[cur_b * 128 + c0], accx);
            atomicAdd(&gsum[cur_b * 128 + c0 + 1], accy);
            if (lane == 0) atomicAdd(gcnt + cur_b, cntf);
            accx = accy = cntf = 0.f;
            cur_b = b;
        }
        accx += h2.x; accy += h2.y; cntf += 1.f;
    }
    atomicAdd(&gsum[cur_b * 128 + c0], accx);
    atomicAdd(&gsum[cur_b * 128 + c0 + 1], accy);
    if (lane == 0) atomicAdd(gcnt + cur_b, cntf);
}

__global__ void graph_kernel(const float* __restrict__ gsum, const float* __restrict__ gcnt,
                             const float* __restrict__ Wg1, const float* __restrict__ bg1,
                             const float* __restrict__ Wg2, const float* __restrict__ bg2,
                             float* __restrict__ graph_emb) {
    __shared__ float gm[8 * 128];
    __shared__ float t1[8 * 128];
    int t = threadIdx.x;
    for (int i = t; i < 1024; i += 256) {
        int b = i >> 7;
        float c = gcnt[b];
        c = c > 1.f ? c : 1.f;
        gm[i] = gsum[i] / c;
    }
    __syncthreads();
    for (int i = t; i < 1024; i += 256) {
        int r = i >> 7, j = i & 127;
        float acc = bg1[j];
        for (int k = 0; k < 128; ++k) acc += gm[r * 128 + k] * Wg1[k * 128 + j];
        t1[i] = acc > 0.f ? acc : (__expf(acc) - 1.f);
    }
    __syncthreads();
    for (int i = t; i < 512; i += 256) {
        int r = i >> 6, j = i & 63;
        float acc = bg2[j];
        for (int k = 0; k < 128; ++k) acc += t1[r * 128 + k] * Wg2[k * 64 + j];
        graph_emb[r * 64 + j] = acc;
    }
}

// ---------------------------------------------------------------- launch

extern "C" void kernel_launch(void* const* d_in, const int* in_sizes, int n_in,
                              void* d_out, int out_size, void* d_ws, size_t ws_size,
                              hipStream_t stream) {
    const float* x         = (const float*)d_in[0];
    const int*   edge_index= (const int*)d_in[1];
    const float* edge_attr = (const float*)d_in[2];
    const int*   batch     = (const int*)d_in[3];
    const float* W_in      = (const float*)d_in[4];
    const float* b_in      = (const float*)d_in[5];
    const float* Wl        = (const float*)d_in[6];
    const float* bl        = (const float*)d_in[7];
    const float* Wr        = (const float*)d_in[8];
    const float* br        = (const float*)d_in[9];
    const float* We        = (const float*)d_in[10];
    const float* att       = (const float*)d_in[11];
    const float* bc        = (const float*)d_in[12];
    const float* ln_g      = (const float*)d_in[13];
    const float* ln_b      = (const float*)d_in[14];
    const float* Wn        = (const float*)d_in[15];
    const float* bn        = (const float*)d_in[16];
    const float* Wg1       = (const float*)d_in[17];
    const float* bg1       = (const float*)d_in[18];
    const float* Wg2       = (const float*)d_in[19];
    const float* bg2       = (const float*)d_in[20];

    const int N_ = in_sizes[3];   // batch is (N,)
    const int E_ = in_sizes[2];   // edge_attr is (E,1)

    const int* src0 = edge_index;
    const int* dst0 = edge_index + E_;

    float* ws = (float*)d_ws;
    float* h      = ws;                              // N*128 f32
    float* gsum   = h + (size_t)N_ * 128;            // 1024
    float* gcnt   = gsum + 1024;                     // 16 (8 used)
    float* easum  = gcnt + 16;                       // N
    int* cnt      = (int*)(easum + N_);              // N
    int* rowstart = cnt + N_;                        // N+2 (pad keeps int2 align)
    int* cursor   = rowstart + N_ + 2;               // N
    int2* csr     = (int2*)(cursor + N_);            // E+N (8B aligned)
    ushort* h_bf  = (ushort*)(csr + (size_t)(E_ + N_));   // N*128
    ushort* x_bf  = h_bf + (size_t)N_ * 128;              // N*32
    ushort* xl_bf = x_bf + (size_t)N_ * 32;               // N*128
    ushort* xr_bf = xl_bf + (size_t)N_ * 128;             // N*128
    ushort* wpack = xr_bf + (size_t)N_ * 128;             // 110592

    float* out_f     = (float*)d_out;
    float* node_emb  = out_f;                               // N*64
    float* graph_emb = out_f + (size_t)N_ * 64;             // 8*64
    float* h_out     = out_f + (size_t)N_ * 64 + 8 * 64;    // N*128

    // gsum, gcnt, easum, cnt contiguous -> one memset
    hipMemsetAsync(gsum, 0, (1024 + 16 + 2 * (size_t)N_) * sizeof(float), stream);

    int nx4 = N_ * 8;  // x float4 count
    pack_cvt_kernel<<<(110592 + nx4 + 255) / 256, 256, 0, stream>>>(
        Wl, Wr, W_in, Wn, x, wpack, x_bf, nx4);
    count_kernel<<<(E_ + 255) / 256, 256, 0, stream>>>(dst0, edge_attr, cnt, easum, E_);
    scan_kernel<<<1, 1024, 0, stream>>>(cnt, easum, rowstart, csr, cursor, N_);
    scatter_kernel<<<(E_ + 255) / 256, 256, 0, stream>>>(src0, dst0, edge_attr, cursor,
                                                         csr, E_);

    mfma_inproj<<<(N_ + 63) / 64, 256, 0, stream>>>(x_bf, wpack + 98304, b_in, h, h_bf, N_);

    for (int l = 0; l < 3; ++l) {
        mfma_proj<<<(N_ + 127) / 128, 256, 0, stream>>>(
            h_bf, wpack + l * 16384, wpack + (3 + l) * 16384,
            bl + l * 128, br + l * 128, xl_bf, xr_bf, N_);
        aggregate_kernel<<<(N_ + 3) / 4, 256, 0, stream>>>(
            h, xl_bf, xr_bf, rowstart, csr, We + l * 128, att + l * 128,
            bc + l * 128, ln_g + l * 128, ln_b + l * 128,
            h_bf, (l == 2) ? h_out : (float*)nullptr, N_);
    }

    mfma_nodeemb<<<(N_ + 63) / 64, 256, 0, stream>>>(h_bf, wpack + 102400, bn, node_emb, N_);
    {
        int total_waves = 2048;
        int chunk = (N_ + total_waves - 1) / total_waves;
        batch_kernel<<<total_waves / 4, 256, 0, stream>>>(h, batch, gsum, gcnt, N_, chunk);
    }
    graph_kernel<<<1, 256, 0, stream>>>(gsum, gcnt, Wg1, bg1, Wg2, bg2, graph_emb);
}

// Round 8
// 562.835 us; speedup vs baseline: 1.3249x; 1.3249x over previous
//
#include <hip/hip_runtime.h>

#define NEG_SLOPE 0.2f
#define LN_EPS 1e-5f

typedef __attribute__((ext_vector_type(8))) short bf16x8;
typedef __attribute__((ext_vector_type(4))) float f32x4;

__device__ __forceinline__ ushort f2bf(float f) {  // round-to-nearest-even
    uint u = __float_as_uint(f);
    u += 0x7fffu + ((u >> 16) & 1u);
    return (ushort)(u >> 16);
}

// ---------------------------------------------------------------- prep kernels

__global__ void count_kernel(const int* __restrict__ dst0, const float* __restrict__ eattr,
                             int* __restrict__ cnt, float* __restrict__ easum, int E_) {
    int e = blockIdx.x * 256 + threadIdx.x;
    if (e >= E_) return;
    int d = dst0[e];
    atomicAdd(&cnt[d], 1);
    atomicAdd(&easum[d], eattr[e]);
}

// -------- 3-phase parallel scan over (cnt[i]+1), with self-loop emission ----
// phase 1: per-block (1024 elems) sums
__global__ __launch_bounds__(256) void scan1_kernel(const int* __restrict__ cnt,
                                                    int* __restrict__ blocksum, int N_) {
    __shared__ int lds[256];
    int t = threadIdx.x;
    int i0 = blockIdx.x * 1024 + t * 4;
    int s = 0;
    if (i0 + 3 < N_) {
        int4 c4 = *(const int4*)(cnt + i0);
        s = c4.x + c4.y + c4.z + c4.w + 4;
    } else {
#pragma unroll
        for (int j = 0; j < 4; ++j)
            if (i0 + j < N_) s += cnt[i0 + j] + 1;
    }
    lds[t] = s;
    __syncthreads();
#pragma unroll
    for (int off = 128; off > 0; off >>= 1) {
        if (t < off) lds[t] += lds[t + off];
        __syncthreads();
    }
    if (t == 0) blocksum[blockIdx.x] = lds[0];
}

// phase 2: one block scans block sums (nb <= 1024) -> exclusive bases + total
__global__ __launch_bounds__(1024) void scan2_kernel(const int* __restrict__ blocksum,
                                                     int* __restrict__ blockbase, int nb,
                                                     int* __restrict__ rowstart, int N_) {
    __shared__ int lds[1024];
    int t = threadIdx.x;
    int v = (t < nb) ? blocksum[t] : 0;
    lds[t] = v;
    __syncthreads();
    for (int off = 1; off < 1024; off <<= 1) {
        int u = (t >= off) ? lds[t - off] : 0;
        __syncthreads();
        lds[t] += u;
        __syncthreads();
    }
    if (t < nb) blockbase[t] = lds[t] - v;
    if (t == 0) rowstart[N_] = lds[nb - 1];
}

// phase 3: block-local scan + emit rowstart / self-loop csr / cursor
__global__ __launch_bounds__(256) void scan3_kernel(const int* __restrict__ cnt,
                                                    const float* __restrict__ easum,
                                                    const int* __restrict__ blockbase,
                                                    int* __restrict__ rowstart,
                                                    int2* __restrict__ csr,
                                                    int* __restrict__ cursor, int N_) {
    __shared__ int lds[256];
    int t = threadIdx.x;
    int i0 = blockIdx.x * 1024 + t * 4;
    int c[4];
    int nv = 0;
    int s = 0;
#pragma unroll
    for (int j = 0; j < 4; ++j) {
        if (i0 + j < N_) { c[j] = cnt[i0 + j]; s += c[j] + 1; nv = j + 1; }
        else c[j] = 0;
    }
    lds[t] = s;
    __syncthreads();
    for (int off = 1; off < 256; off <<= 1) {
        int u = (t >= off) ? lds[t - off] : 0;
        __syncthreads();
        lds[t] += u;
        __syncthreads();
    }
    int run = blockbase[blockIdx.x] + lds[t] - s;
#pragma unroll
    for (int j = 0; j < 4; ++j) {
        if (j < nv) {
            int i = i0 + j;
            rowstart[i] = run;
            int cc = c[j];
            csr[run] = make_int2(i, __float_as_int(easum[i] / (float)(cc > 1 ? cc : 1)));
            cursor[i] = run + 1;
            run += cc + 1;
        }
    }
}

__global__ void scatter_kernel(const int* __restrict__ src0, const int* __restrict__ dst0,
                               const float* __restrict__ eattr, int* __restrict__ cursor,
                               int2* __restrict__ csr, int E_) {
    int e = blockIdx.x * 256 + threadIdx.x;
    if (e >= E_) return;
    int d = dst0[e];
    int p = atomicAdd(&cursor[d], 1);
    csr[p] = make_int2(src0[e], __float_as_int(eattr[e]));
}

// pack weights into bf16 MFMA B-fragment order, + convert x to bf16.
// wpack: [0,98304) Wl0..2,Wr0..2 (128x128); [98304,102400) W_in (32x128);
// [102400,110592) Wn (128x64).
__global__ void pack_cvt_kernel(const float* __restrict__ Wl, const float* __restrict__ Wr,
                                const float* __restrict__ Win, const float* __restrict__ Wn,
                                const float* __restrict__ x, ushort* __restrict__ wpack,
                                ushort* __restrict__ xb, int nx4) {
    int idx = blockIdx.x * 256 + threadIdx.x;
    if (idx < 110592) {
        const float* src; int Ncol, rel;
        if (idx < 98304) {
            int m = idx >> 14; rel = idx & 16383;
            src = m < 3 ? Wl + m * 16384 : Wr + (m - 3) * 16384;
            Ncol = 128;
        } else if (idx < 102400) {
            rel = idx - 98304; src = Win; Ncol = 128;
        } else {
            rel = idx - 102400; src = Wn; Ncol = 64;
        }
        int j = rel & 7, lane = (rel >> 3) & 63, rest = rel >> 9;
        int nc16 = Ncol >> 4;
        int c = rest % nc16, ks = rest / nc16;
        int k = ks * 32 + ((lane >> 4) << 3) + j;
        int col = c * 16 + (lane & 15);
        wpack[idx] = f2bf(src[k * Ncol + col]);
    } else {
        int i = idx - 110592;
        if (i < nx4) {
            float4 v = *(const float4*)(x + (size_t)i * 4);
            ushort4 o;
            o.x = f2bf(v.x); o.y = f2bf(v.y); o.z = f2bf(v.z); o.w = f2bf(v.w);
            *(ushort4*)(xb + (size_t)i * 4) = o;
        }
    }
}

// ---------------------------------------------------------------- MFMA GEMMs
// A-frag: row = lane&15, k = (lane>>4)*8 + j. D-frag: col = lane&15, row = (lane>>4)*4 + reg.

__global__ __launch_bounds__(256) void mfma_inproj(
    const ushort* __restrict__ x_bf, const ushort* __restrict__ Wp,
    const float* __restrict__ b_in, float* __restrict__ h, ushort* __restrict__ h_bf, int N_) {
    int wave = threadIdx.x >> 6, lane = threadIdx.x & 63;
    int row0 = blockIdx.x * 64 + wave * 16;
    int arow = row0 + (lane & 15); if (arow >= N_) arow = N_ - 1;
    int koff = (lane >> 4) * 8;
    bf16x8 a = *(const bf16x8*)(x_bf + (size_t)arow * 32 + koff);
    f32x4 acc[8];
#pragma unroll
    for (int c = 0; c < 8; ++c) acc[c] = {0.f, 0.f, 0.f, 0.f};
#pragma unroll
    for (int c = 0; c < 8; ++c) {
        bf16x8 b = *(const bf16x8*)(Wp + ((size_t)c * 64 + lane) * 8);
        acc[c] = __builtin_amdgcn_mfma_f32_16x16x32_bf16(a, b, acc[c], 0, 0, 0);
    }
    int srow = row0 + (lane >> 4) * 4;
    int scol = lane & 15;
#pragma unroll
    for (int c = 0; c < 8; ++c) {
        float bi = b_in[c * 16 + scol];
#pragma unroll
        for (int r = 0; r < 4; ++r) {
            int row = srow + r;
            if (row < N_) {
                float v = acc[c][r] + bi;
                h[(size_t)row * 128 + c * 16 + scol] = v;
                h_bf[(size_t)row * 128 + c * 16 + scol] = f2bf(v);
            }
        }
    }
}

// layer proj: 128 rows/block, wave = 32 rows (2 A-frags per B-frag load)
__global__ __launch_bounds__(256, 1) void mfma_proj(
    const ushort* __restrict__ h_bf, const ushort* __restrict__ Wlp,
    const ushort* __restrict__ Wrp, const float* __restrict__ bl, const float* __restrict__ br,
    ushort* __restrict__ xl, ushort* __restrict__ xr, int N_) {
    int wave = threadIdx.x >> 6, lane = threadIdx.x & 63;
    int row0 = blockIdx.x * 128 + wave * 32;
    int ar0 = row0 + (lane & 15); if (ar0 >= N_) ar0 = N_ - 1;
    int ar1 = row0 + 16 + (lane & 15); if (ar1 >= N_) ar1 = N_ - 1;
    int koff = (lane >> 4) * 8;
    f32x4 accL[2][8], accR[2][8];
#pragma unroll
    for (int g = 0; g < 2; ++g)
#pragma unroll
        for (int c = 0; c < 8; ++c) { accL[g][c] = {0.f, 0.f, 0.f, 0.f}; accR[g][c] = {0.f, 0.f, 0.f, 0.f}; }
#pragma unroll
    for (int ks = 0; ks < 4; ++ks) {
        bf16x8 a0 = *(const bf16x8*)(h_bf + (size_t)ar0 * 128 + ks * 32 + koff);
        bf16x8 a1 = *(const bf16x8*)(h_bf + (size_t)ar1 * 128 + ks * 32 + koff);
        const ushort* wl = Wlp + ((size_t)ks * 8 * 64 + lane) * 8;
        const ushort* wr = Wrp + ((size_t)ks * 8 * 64 + lane) * 8;
#pragma unroll
        for (int c = 0; c < 8; ++c) {
            bf16x8 bL = *(const bf16x8*)(wl + c * 512);
            accL[0][c] = __builtin_amdgcn_mfma_f32_16x16x32_bf16(a0, bL, accL[0][c], 0, 0, 0);
            accL[1][c] = __builtin_amdgcn_mfma_f32_16x16x32_bf16(a1, bL, accL[1][c], 0, 0, 0);
            bf16x8 bR = *(const bf16x8*)(wr + c * 512);
            accR[0][c] = __builtin_amdgcn_mfma_f32_16x16x32_bf16(a0, bR, accR[0][c], 0, 0, 0);
            accR[1][c] = __builtin_amdgcn_mfma_f32_16x16x32_bf16(a1, bR, accR[1][c], 0, 0, 0);
        }
    }
    int scol = lane & 15;
#pragma unroll
    for (int g = 0; g < 2; ++g) {
        int srow = row0 + g * 16 + (lane >> 4) * 4;
#pragma unroll
        for (int c = 0; c < 8; ++c) {
            float bLv = bl[c * 16 + scol];
            float bRv = br[c * 16 + scol];
#pragma unroll
            for (int r = 0; r < 4; ++r) {
                int row = srow + r;
                if (row < N_) {
                    xl[(size_t)row * 128 + c * 16 + scol] = f2bf(accL[g][c][r] + bLv);
                    xr[(size_t)row * 128 + c * 16 + scol] = f2bf(accR[g][c][r] + bRv);
                }
            }
        }
    }
}

__global__ __launch_bounds__(256) void mfma_nodeemb(
    const ushort* __restrict__ h_bf, const ushort* __restrict__ Wp,
    const float* __restrict__ bn, float* __restrict__ node_emb, int N_) {
    int wave = threadIdx.x >> 6, lane = threadIdx.x & 63;
    int row0 = blockIdx.x * 64 + wave * 16;
    int arow = row0 + (lane & 15); if (arow >= N_) arow = N_ - 1;
    int koff = (lane >> 4) * 8;
    f32x4 acc[4];
#pragma unroll
    for (int c = 0; c < 4; ++c) acc[c] = {0.f, 0.f, 0.f, 0.f};
#pragma unroll
    for (int ks = 0; ks < 4; ++ks) {
        bf16x8 a = *(const bf16x8*)(h_bf + (size_t)arow * 128 + ks * 32 + koff);
#pragma unroll
        for (int c = 0; c < 4; ++c) {
            bf16x8 b = *(const bf16x8*)(Wp + ((size_t)(ks * 4 + c) * 64 + lane) * 8);
            acc[c] = __builtin_amdgcn_mfma_f32_16x16x32_bf16(a, b, acc[c], 0, 0, 0);
        }
    }
    int srow = row0 + (lane >> 4) * 4;
    int scol = lane & 15;
#pragma unroll
    for (int c = 0; c < 4; ++c) {
        float bi = bn[c * 16 + scol];
#pragma unroll
        for (int r = 0; r < 4; ++r) {
            int row = srow + r;
            if (row < N_) node_emb[(size_t)row * 64 + c * 16 + scol] = acc[c][r] + bi;
        }
    }
}

// ---------------------------------------------------------------- per-node aggregation
// DPP 16-lane head reduce (full-rate VALU).

__device__ __forceinline__ float head16_sum(float x) {
    int v;
    v = __builtin_amdgcn_update_dpp(0, __float_as_int(x), 0xB1, 0xF, 0xF, true);
    x += __int_as_float(v);
    v = __builtin_amdgcn_update_dpp(0, __float_as_int(x), 0x4E, 0xF, 0xF, true);
    x += __int_as_float(v);
    v = __builtin_amdgcn_update_dpp(0, __float_as_int(x), 0x141, 0xF, 0xF, true);
    x += __int_as_float(v);
    v = __builtin_amdgcn_update_dpp(0, __float_as_int(x), 0x140, 0xF, 0xF, true);
    x += __int_as_float(v);
    return x;
}

// no-max softmax (alpha is O(1) for this model; clamp +-60 guards exp).
__device__ __forceinline__ void edge_step(const uint* __restrict__ xlw,
                                          const int2* __restrict__ csr, int p, uint lane,
                                          float we2x, float we2y, float xr2x, float xr2y,
                                          float atx, float aty,
                                          float& d, float& ax, float& ay) {
    int2 e = csr[p];
    uint off = ((uint)e.x << 6) + lane;
    uint va = xlw[off];
    float xax = __uint_as_float(va << 16);
    float xay = __uint_as_float(va & 0xffff0000u);
    float ea = __int_as_float(e.y);
    float mx = xax + fmaf(ea, we2x, xr2x);
    float my = xay + fmaf(ea, we2y, xr2y);
    mx = fmaxf(mx, NEG_SLOPE * mx);
    my = fmaxf(my, NEG_SLOPE * my);
    float al = head16_sum(fmaf(my, aty, mx * atx));
    al = fminf(fmaxf(al, -60.f), 60.f);
    float pe = __expf(al);
    d += pe;
    ax = fmaf(pe, xax, ax);
    ay = fmaf(pe, xay, ay);
}

__global__ __launch_bounds__(256) void aggregate_kernel(
    float* __restrict__ h, const ushort* __restrict__ xl, const ushort* __restrict__ xr,
    const int* __restrict__ rowstart, const int2* __restrict__ csr,
    const float* __restrict__ We, const float* __restrict__ att, const float* __restrict__ bc,
    const float* __restrict__ ln_g, const float* __restrict__ ln_b,
    ushort* __restrict__ h_bf, float* __restrict__ h_out, int N_) {
    int wave = threadIdx.x >> 6;
    uint lane = threadIdx.x & 63;
    int n = blockIdx.x * 4 + wave;
    if (n >= N_) return;
    int c0 = lane * 2;
    int head = lane >> 4;
    const uint* xlw = (const uint*)xl;
    uint vr = *(const uint*)(xr + (size_t)n * 128 + c0);
    float xr2x = __uint_as_float(vr << 16);
    float xr2y = __uint_as_float(vr & 0xffff0000u);
    float2 we2 = *(const float2*)(We + c0);
    float2 at2 = *(const float2*)(att + head * 32 + (c0 & 31));
    int rs = rowstart[n], re = rowstart[n + 1];
    float d0 = 0.f, ax0 = 0.f, ay0 = 0.f;
    float d1 = 0.f, ax1 = 0.f, ay1 = 0.f;
    float d2 = 0.f, ax2 = 0.f, ay2 = 0.f;
    float d3 = 0.f, ax3 = 0.f, ay3 = 0.f;
    int p = rs;
    for (; p + 4 <= re; p += 4) {
        edge_step(xlw, csr, p,     lane, we2.x, we2.y, xr2x, xr2y, at2.x, at2.y, d0, ax0, ay0);
        edge_step(xlw, csr, p + 1, lane, we2.x, we2.y, xr2x, xr2y, at2.x, at2.y, d1, ax1, ay1);
        edge_step(xlw, csr, p + 2, lane, we2.x, we2.y, xr2x, xr2y, at2.x, at2.y, d2, ax2, ay2);
        edge_step(xlw, csr, p + 3, lane, we2.x, we2.y, xr2x, xr2y, at2.x, at2.y, d3, ax3, ay3);
    }
    for (; p < re; ++p)
        edge_step(xlw, csr, p, lane, we2.x, we2.y, xr2x, xr2y, at2.x, at2.y, d0, ax0, ay0);
    float den = (d0 + d1) + (d2 + d3);
    float accx = (ax0 + ax1) + (ax2 + ax3);
    float accy = (ay0 + ay1) + (ay2 + ay3);
    float inv = 1.f / den;
    float2 bc2 = *(const float2*)(bc + c0);
    float ox = accx * inv + bc2.x;
    float oy = accy * inv + bc2.y;
    ox = ox > 0.f ? ox : (__expf(ox) - 1.f);  // elu
    oy = oy > 0.f ? oy : (__expf(oy) - 1.f);
    float2 h2 = *(const float2*)(h + (size_t)n * 128 + c0);
    float tx = h2.x + ox, ty = h2.y + oy;
    // one-pass LN: reduce sum and sumsq together
    float s1v = tx + ty;
    float s2v = tx * tx + ty * ty;
#pragma unroll
    for (int m = 1; m < 64; m <<= 1) {
        s1v += __shfl_xor(s1v, m);
        s2v += __shfl_xor(s2v, m);
    }
    float mu = s1v * (1.f / 128.f);
    float var = s2v * (1.f / 128.f) - mu * mu;
    float rstd = rsqrtf(var + LN_EPS);
    float2 g2 = *(const float2*)(ln_g + c0);
    float2 b2 = *(const float2*)(ln_b + c0);
    float2 hn;
    hn.x = (tx - mu) * rstd * g2.x + b2.x;
    hn.y = (ty - mu) * rstd * g2.y + b2.y;
    *(float2*)(h + (size_t)n * 128 + c0) = hn;
    uint packed = (uint)f2bf(hn.x) | ((uint)f2bf(hn.y) << 16);
    *(uint*)(h_bf + (size_t)n * 128 + c0) = packed;
    if (h_out) *(float2*)(h_out + (size_t)n * 128 + c0) = hn;
}

// ---------------------------------------------------------------- outputs

__global__ __launch_bounds__(256) void batch_kernel(
    const float* __restrict__ h, const int* __restrict__ batch,
    float* __restrict__ gsum, float* __restrict__ gcnt, int N_, int chunk) {
    int wave_id = (blockIdx.x * 256 + threadIdx.x) >> 6;
    int lane = threadIdx.x & 63;
    int w0 = wave_id * chunk;
    if (w0 >= N_) return;
    int w1 = w0 + chunk; if (w1 > N_) w1 = N_;
    int c0 = lane * 2;
    int cur_b = batch[w0];
    float accx = 0.f, accy = 0.f, cntf = 0.f;
    for (int n = w0; n < w1; ++n) {
        float2 h2 = *(const float2*)(h + (size_t)n * 128 + c0);
        int b = batch[n];
        if (b != cur_b) {
            atomicAdd(&gsum[cur_b * 128 + c0], accx);
            atomicAdd(&gsum[cur_b * 128 + c0 + 1], accy);
            if (lane == 0) atomicAdd(gcnt + cur_b, cntf);
            accx = accy = cntf = 0.f;
            cur_b = b;
        }
        accx += h2.x; accy += h2.y; cntf += 1.f;
    }
    atomicAdd(&gsum[cur_b * 128 + c0], accx);
    atomicAdd(&gsum[cur_b * 128 + c0 + 1], accy);
    if (lane == 0) atomicAdd(gcnt + cur_b, cntf);
}

__global__ void graph_kernel(const float* __restrict__ gsum, const float* __restrict__ gcnt,
                             const float* __restrict__ Wg1, const float* __restrict__ bg1,
                             const float* __restrict__ Wg2, const float* __restrict__ bg2,
                             float* __restrict__ graph_emb) {
    __shared__ float gm[8 * 128];
    __shared__ float t1[8 * 128];
    int t = threadIdx.x;
    for (int i = t; i < 1024; i += 256) {
        int b = i >> 7;
        float c = gcnt[b];
        c = c > 1.f ? c : 1.f;
        gm[i] = gsum[i] / c;
    }
    __syncthreads();
    for (int i = t; i < 1024; i += 256) {
        int r = i >> 7, j = i & 127;
        float acc = bg1[j];
        for (int k = 0; k < 128; ++k) acc += gm[r * 128 + k] * Wg1[k * 128 + j];
        t1[i] = acc > 0.f ? acc : (__expf(acc) - 1.f);
    }
    __syncthreads();
    for (int i = t; i < 512; i += 256) {
        int r = i >> 6, j = i & 63;
        float acc = bg2[j];
        for (int k = 0; k < 128; ++k) acc += t1[r * 128 + k] * Wg2[k * 64 + j];
        graph_emb[r * 64 + j] = acc;
    }
}

// ---------------------------------------------------------------- launch

extern "C" void kernel_launch(void* const* d_in, const int* in_sizes, int n_in,
                              void* d_out, int out_size, void* d_ws, size_t ws_size,
                              hipStream_t stream) {
    const float* x         = (const float*)d_in[0];
    const int*   edge_index= (const int*)d_in[1];
    const float* edge_attr = (const float*)d_in[2];
    const int*   batch     = (const int*)d_in[3];
    const float* W_in      = (const float*)d_in[4];
    const float* b_in      = (const float*)d_in[5];
    const float* Wl        = (const float*)d_in[6];
    const float* bl        = (const float*)d_in[7];
    const float* Wr        = (const float*)d_in[8];
    const float* br        = (const float*)d_in[9];
    const float* We        = (const float*)d_in[10];
    const float* att       = (const float*)d_in[11];
    const float* bc        = (const float*)d_in[12];
    const float* ln_g      = (const float*)d_in[13];
    const float* ln_b      = (const float*)d_in[14];
    const float* Wn        = (const float*)d_in[15];
    const float* bn        = (const float*)d_in[16];
    const float* Wg1       = (const float*)d_in[17];
    const float* bg1       = (const float*)d_in[18];
    const float* Wg2       = (const float*)d_in[19];
    const float* bg2       = (const float*)d_in[20];

    const int N_ = in_sizes[3];   // batch is (N,)
    const int E_ = in_sizes[2];   // edge_attr is (E,1)

    const int* src0 = edge_index;
    const int* dst0 = edge_index + E_;

    float* ws = (float*)d_ws;
    float* h      = ws;                              // N*128 f32
    float* gsum   = h + (size_t)N_ * 128;            // 1024
    float* gcnt   = gsum + 1024;                     // 16 (8 used)
    float* easum  = gcnt + 16;                       // N
    int* cnt      = (int*)(easum + N_);              // N
    int* rowstart = cnt + N_;                        // N+2 (pad keeps int2 align)
    int* cursor   = rowstart + N_ + 2;               // N
    int* blocksum = cursor + N_;                     // 1024
    int* blockbase= blocksum + 1024;                 // 1024
    int2* csr     = (int2*)(blockbase + 1024);       // E+N (8B aligned)
    ushort* h_bf  = (ushort*)(csr + (size_t)(E_ + N_));   // N*128
    ushort* x_bf  = h_bf + (size_t)N_ * 128;              // N*32
    ushort* xl_bf = x_bf + (size_t)N_ * 32;               // N*128
    ushort* xr_bf = xl_bf + (size_t)N_ * 128;             // N*128
    ushort* wpack = xr_bf + (size_t)N_ * 128;             // 110592

    float* out_f     = (float*)d_out;
    float* node_emb  = out_f;                               // N*64
    float* graph_emb = out_f + (size_t)N_ * 64;             // 8*64
    float* h_out     = out_f + (size_t)N_ * 64 + 8 * 64;    // N*128

    // gsum, gcnt, easum, cnt contiguous -> one memset
    hipMemsetAsync(gsum, 0, (1024 + 16 + 2 * (size_t)N_) * sizeof(float), stream);

    int nx4 = N_ * 8;  // x float4 count
    pack_cvt_kernel<<<(110592 + nx4 + 255) / 256, 256, 0, stream>>>(
        Wl, Wr, W_in, Wn, x, wpack, x_bf, nx4);
    count_kernel<<<(E_ + 255) / 256, 256, 0, stream>>>(dst0, edge_attr, cnt, easum, E_);

    int nb = (N_ + 1023) / 1024;  // <= 1024
    scan1_kernel<<<nb, 256, 0, stream>>>(cnt, blocksum, N_);
    scan2_kernel<<<1, 1024, 0, stream>>>(blocksum, blockbase, nb, rowstart, N_);
    scan3_kernel<<<nb, 256, 0, stream>>>(cnt, easum, blockbase, rowstart, csr, cursor, N_);

    scatter_kernel<<<(E_ + 255) / 256, 256, 0, stream>>>(src0, dst0, edge_attr, cursor,
                                                         csr, E_);

    mfma_inproj<<<(N_ + 63) / 64, 256, 0, stream>>>(x_bf, wpack + 98304, b_in, h, h_bf, N_);

    for (int l = 0; l < 3; ++l) {
        mfma_proj<<<(N_ + 127) / 128, 256, 0, stream>>>(
            h_bf, wpack + l * 16384, wpack + (3 + l) * 16384,
            bl + l * 128, br + l * 128, xl_bf, xr_bf, N_);
        aggregate_kernel<<<(N_ + 3) / 4, 256, 0, stream>>>(
            h, xl_bf, xr_bf, rowstart, csr, We + l * 128, att + l * 128,
            bc + l * 128, ln_g + l * 128, ln_b + l * 128,
            h_bf, (l == 2) ? h_out : (float*)nullptr, N_);
    }

    mfma_nodeemb<<<(N_ + 63) / 64, 256, 0, stream>>>(h_bf, wpack + 102400, bn, node_emb, N_);
    {
        int total_waves = 2048;
        int chunk = (N_ + total_waves - 1) / total_waves;
        batch_kernel<<<total_waves / 4, 256, 0, stream>>>(h, batch, gsum, gcnt, N_, chunk);
    }
    graph_kernel<<<1, 256, 0, stream>>>(gsum, gcnt, Wg1, bg1, Wg2, bg2, graph_emb);
}

// Round 10
// 499.712 us; speedup vs baseline: 1.4922x; 1.1263x over previous
//
#include <hip/hip_runtime.h>

#define NEG_SLOPE 0.2f
#define LN_EPS 1e-5f

typedef __attribute__((ext_vector_type(8))) short bf16x8;
typedef __attribute__((ext_vector_type(4))) float f32x4;

__device__ __forceinline__ ushort f2bf(float f) {  // round-to-nearest-even
    uint u = __float_as_uint(f);
    u += 0x7fffu + ((u >> 16) & 1u);
    return (ushort)(u >> 16);
}

// ---------------------------------------------------------------- prep kernels

// one int atomic per edge; returned old value = rank of edge within its dst bin
__global__ void count_kernel(const int* __restrict__ dst0, int* __restrict__ cnt,
                             int* __restrict__ rank, int E_) {
    int e = blockIdx.x * 256 + threadIdx.x;
    if (e >= E_) return;
    rank[e] = atomicAdd(&cnt[dst0[e]], 1);
}

// -------- 3-phase parallel scan over (cnt[i]+1) ----------------------------
__global__ __launch_bounds__(256) void scan1_kernel(const int* __restrict__ cnt,
                                                    int* __restrict__ blocksum, int N_) {
    __shared__ int lds[256];
    int t = threadIdx.x;
    int i0 = blockIdx.x * 1024 + t * 4;
    int s = 0;
    if (i0 + 3 < N_) {
        int4 c4 = *(const int4*)(cnt + i0);
        s = c4.x + c4.y + c4.z + c4.w + 4;
    } else {
#pragma unroll
        for (int j = 0; j < 4; ++j)
            if (i0 + j < N_) s += cnt[i0 + j] + 1;
    }
    lds[t] = s;
    __syncthreads();
#pragma unroll
    for (int off = 128; off > 0; off >>= 1) {
        if (t < off) lds[t] += lds[t + off];
        __syncthreads();
    }
    if (t == 0) blocksum[blockIdx.x] = lds[0];
}

__global__ __launch_bounds__(1024) void scan2_kernel(const int* __restrict__ blocksum,
                                                     int* __restrict__ blockbase, int nb,
                                                     int* __restrict__ rowstart, int N_) {
    __shared__ int lds[1024];
    int t = threadIdx.x;
    int v = (t < nb) ? blocksum[t] : 0;
    lds[t] = v;
    __syncthreads();
    for (int off = 1; off < 1024; off <<= 1) {
        int u = (t >= off) ? lds[t - off] : 0;
        __syncthreads();
        lds[t] += u;
        __syncthreads();
    }
    if (t < nb) blockbase[t] = lds[t] - v;
    if (t == 0) rowstart[N_] = lds[nb - 1];
}

__global__ __launch_bounds__(256) void scan3_kernel(const int* __restrict__ cnt,
                                                    const int* __restrict__ blockbase,
                                                    int* __restrict__ rowstart, int N_) {
    __shared__ int lds[256];
    int t = threadIdx.x;
    int i0 = blockIdx.x * 1024 + t * 4;
    int c[4];
    int nv = 0;
    int s = 0;
#pragma unroll
    for (int j = 0; j < 4; ++j) {
        if (i0 + j < N_) { c[j] = cnt[i0 + j]; s += c[j] + 1; nv = j + 1; }
        else c[j] = 0;
    }
    lds[t] = s;
    __syncthreads();
    for (int off = 1; off < 256; off <<= 1) {
        int u = (t >= off) ? lds[t - off] : 0;
        __syncthreads();
        lds[t] += u;
        __syncthreads();
    }
    int run = blockbase[blockIdx.x] + lds[t] - s;
#pragma unroll
    for (int j = 0; j < 4; ++j) {
        if (j < nv) {
            rowstart[i0 + j] = run;
            run += c[j] + 1;
        }
    }
}

// atomic-free scatter: position = rowstart[dst] + 1 + rank[e]
__global__ void scatter_kernel(const int* __restrict__ src0, const int* __restrict__ dst0,
                               const float* __restrict__ eattr, const int* __restrict__ rank,
                               const int* __restrict__ rowstart, int2* __restrict__ csr, int E_) {
    int e = blockIdx.x * 256 + threadIdx.x;
    if (e >= E_) return;
    int d = dst0[e];
    int p = rowstart[d] + 1 + rank[e];
    csr[p] = make_int2(src0[e], __float_as_int(eattr[e]));
}

// self-loop ea = mean of incoming ea, computed from the built CSR (no atomics)
__global__ void selfloop_kernel(const int* __restrict__ rowstart, int2* __restrict__ csr,
                                int N_) {
    int n = blockIdx.x * 256 + threadIdx.x;
    if (n >= N_) return;
    int rs = rowstart[n], re = rowstart[n + 1];
    float s = 0.f;
    for (int p = rs + 1; p < re; ++p) s += __int_as_float(csr[p].y);
    int c = re - rs - 1;
    csr[rs] = make_int2(n, __float_as_int(s / (float)(c > 1 ? c : 1)));
}

// pack weights into bf16 MFMA B-fragment order, + convert x to bf16.
// wpack: [0,98304) Wl0..2,Wr0..2 (128x128); [98304,102400) W_in (32x128);
// [102400,110592) Wn (128x64).
__global__ void pack_cvt_kernel(const float* __restrict__ Wl, const float* __restrict__ Wr,
                                const float* __restrict__ Win, const float* __restrict__ Wn,
                                const float* __restrict__ x, ushort* __restrict__ wpack,
                                ushort* __restrict__ xb, int nx4) {
    int idx = blockIdx.x * 256 + threadIdx.x;
    if (idx < 110592) {
        const float* src; int Ncol, rel;
        if (idx < 98304) {
            int m = idx >> 14; rel = idx & 16383;
            src = m < 3 ? Wl + m * 16384 : Wr + (m - 3) * 16384;
            Ncol = 128;
        } else if (idx < 102400) {
            rel = idx - 98304; src = Win; Ncol = 128;
        } else {
            rel = idx - 102400; src = Wn; Ncol = 64;
        }
        int j = rel & 7, lane = (rel >> 3) & 63, rest = rel >> 9;
        int nc16 = Ncol >> 4;
        int c = rest % nc16, ks = rest / nc16;
        int k = ks * 32 + ((lane >> 4) << 3) + j;
        int col = c * 16 + (lane & 15);
        wpack[idx] = f2bf(src[k * Ncol + col]);
    } else {
        int i = idx - 110592;
        if (i < nx4) {
            float4 v = *(const float4*)(x + (size_t)i * 4);
            ushort4 o;
            o.x = f2bf(v.x); o.y = f2bf(v.y); o.z = f2bf(v.z); o.w = f2bf(v.w);
            *(ushort4*)(xb + (size_t)i * 4) = o;
        }
    }
}

// ---------------------------------------------------------------- MFMA GEMMs
// A-frag: row = lane&15, k = (lane>>4)*8 + j. D-frag: col = lane&15, row = (lane>>4)*4 + reg.

__global__ __launch_bounds__(256) void mfma_inproj(
    const ushort* __restrict__ x_bf, const ushort* __restrict__ Wp,
    const float* __restrict__ b_in, float* __restrict__ h, ushort* __restrict__ h_bf, int N_) {
    int wave = threadIdx.x >> 6, lane = threadIdx.x & 63;
    int row0 = blockIdx.x * 64 + wave * 16;
    int arow = row0 + (lane & 15); if (arow >= N_) arow = N_ - 1;
    int koff = (lane >> 4) * 8;
    bf16x8 a = *(const bf16x8*)(x_bf + (size_t)arow * 32 + koff);
    f32x4 acc[8];
#pragma unroll
    for (int c = 0; c < 8; ++c) acc[c] = {0.f, 0.f, 0.f, 0.f};
#pragma unroll
    for (int c = 0; c < 8; ++c) {
        bf16x8 b = *(const bf16x8*)(Wp + ((size_t)c * 64 + lane) * 8);
        acc[c] = __builtin_amdgcn_mfma_f32_16x16x32_bf16(a, b, acc[c], 0, 0, 0);
    }
    int srow = row0 + (lane >> 4) * 4;
    int scol = lane & 15;
#pragma unroll
    for (int c = 0; c < 8; ++c) {
        float bi = b_in[c * 16 + scol];
#pragma unroll
        for (int r = 0; r < 4; ++r) {
            int row = srow + r;
            if (row < N_) {
                float v = acc[c][r] + bi;
                h[(size_t)row * 128 + c * 16 + scol] = v;
                h_bf[(size_t)row * 128 + c * 16 + scol] = f2bf(v);
            }
        }
    }
}

// layer proj: 128 rows/block, wave = 32 rows (2 A-frags per B-frag load)
__global__ __launch_bounds__(256, 1) void mfma_proj(
    const ushort* __restrict__ h_bf, const ushort* __restrict__ Wlp,
    const ushort* __restrict__ Wrp, const float* __restrict__ bl, const float* __restrict__ br,
    ushort* __restrict__ xl, ushort* __restrict__ xr, int N_) {
    int wave = threadIdx.x >> 6, lane = threadIdx.x & 63;
    int row0 = blockIdx.x * 128 + wave * 32;
    int ar0 = row0 + (lane & 15); if (ar0 >= N_) ar0 = N_ - 1;
    int ar1 = row0 + 16 + (lane & 15); if (ar1 >= N_) ar1 = N_ - 1;
    int koff = (lane >> 4) * 8;
    f32x4 accL[2][8], accR[2][8];
#pragma unroll
    for (int g = 0; g < 2; ++g)
#pragma unroll
        for (int c = 0; c < 8; ++c) { accL[g][c] = {0.f, 0.f, 0.f, 0.f}; accR[g][c] = {0.f, 0.f, 0.f, 0.f}; }
#pragma unroll
    for (int ks = 0; ks < 4; ++ks) {
        bf16x8 a0 = *(const bf16x8*)(h_bf + (size_t)ar0 * 128 + ks * 32 + koff);
        bf16x8 a1 = *(const bf16x8*)(h_bf + (size_t)ar1 * 128 + ks * 32 + koff);
        const ushort* wl = Wlp + ((size_t)ks * 8 * 64 + lane) * 8;
        const ushort* wr = Wrp + ((size_t)ks * 8 * 64 + lane) * 8;
#pragma unroll
        for (int c = 0; c < 8; ++c) {
            bf16x8 bL = *(const bf16x8*)(wl + c * 512);
            accL[0][c] = __builtin_amdgcn_mfma_f32_16x16x32_bf16(a0, bL, accL[0][c], 0, 0, 0);
            accL[1][c] = __builtin_amdgcn_mfma_f32_16x16x32_bf16(a1, bL, accL[1][c], 0, 0, 0);
            bf16x8 bR = *(const bf16x8*)(wr + c * 512);
            accR[0][c] = __builtin_amdgcn_mfma_f32_16x16x32_bf16(a0, bR, accR[0][c], 0, 0, 0);
            accR[1][c] = __builtin_amdgcn_mfma_f32_16x16x32_bf16(a1, bR, accR[1][c], 0, 0, 0);
        }
    }
    int scol = lane & 15;
#pragma unroll
    for (int g = 0; g < 2; ++g) {
        int srow = row0 + g * 16 + (lane >> 4) * 4;
#pragma unroll
        for (int c = 0; c < 8; ++c) {
            float bLv = bl[c * 16 + scol];
            float bRv = br[c * 16 + scol];
#pragma unroll
            for (int r = 0; r < 4; ++r) {
                int row = srow + r;
                if (row < N_) {
                    xl[(size_t)row * 128 + c * 16 + scol] = f2bf(accL[g][c][r] + bLv);
                    xr[(size_t)row * 128 + c * 16 + scol] = f2bf(accR[g][c][r] + bRv);
                }
            }
        }
    }
}

__global__ __launch_bounds__(256) void mfma_nodeemb(
    const ushort* __restrict__ h_bf, const ushort* __restrict__ Wp,
    const float* __restrict__ bn, float* __restrict__ node_emb, int N_) {
    int wave = threadIdx.x >> 6, lane = threadIdx.x & 63;
    int row0 = blockIdx.x * 64 + wave * 16;
    int arow = row0 + (lane & 15); if (arow >= N_) arow = N_ - 1;
    int koff = (lane >> 4) * 8;
    f32x4 acc[4];
#pragma unroll
    for (int c = 0; c < 4; ++c) acc[c] = {0.f, 0.f, 0.f, 0.f};
#pragma unroll
    for (int ks = 0; ks < 4; ++ks) {
        bf16x8 a = *(const bf16x8*)(h_bf + (size_t)arow * 128 + ks * 32 + koff);
#pragma unroll
        for (int c = 0; c < 4; ++c) {
            bf16x8 b = *(const bf16x8*)(Wp + ((size_t)(ks * 4 + c) * 64 + lane) * 8);
            acc[c] = __builtin_amdgcn_mfma_f32_16x16x32_bf16(a, b, acc[c], 0, 0, 0);
        }
    }
    int srow = row0 + (lane >> 4) * 4;
    int scol = lane & 15;
#pragma unroll
    for (int c = 0; c < 4; ++c) {
        float bi = bn[c * 16 + scol];
#pragma unroll
        for (int r = 0; r < 4; ++r) {
            int row = srow + r;
            if (row < N_) node_emb[(size_t)row * 64 + c * 16 + scol] = acc[c][r] + bi;
        }
    }
}

// ---------------------------------------------------------------- per-node aggregation
// DPP 16-lane head reduce (full-rate VALU).

__device__ __forceinline__ float head16_sum(float x) {
    int v;
    v = __builtin_amdgcn_update_dpp(0, __float_as_int(x), 0xB1, 0xF, 0xF, true);
    x += __int_as_float(v);
    v = __builtin_amdgcn_update_dpp(0, __float_as_int(x), 0x4E, 0xF, 0xF, true);
    x += __int_as_float(v);
    v = __builtin_amdgcn_update_dpp(0, __float_as_int(x), 0x141, 0xF, 0xF, true);
    x += __int_as_float(v);
    v = __builtin_amdgcn_update_dpp(0, __float_as_int(x), 0x140, 0xF, 0xF, true);
    x += __int_as_float(v);
    return x;
}

// no-max softmax (alpha is O(1) for this model; clamp +-60 guards exp).
__device__ __forceinline__ void edge_step(const uint* __restrict__ xlw,
                                          const int2* __restrict__ csr, int p, uint lane,
                                          float we2x, float we2y, float xr2x, float xr2y,
                                          float atx, float aty,
                                          float& d, float& ax, float& ay) {
    int2 e = csr[p];
    uint off = ((uint)e.x << 6) + lane;
    uint va = xlw[off];
    float xax = __uint_as_float(va << 16);
    float xay = __uint_as_float(va & 0xffff0000u);
    float ea = __int_as_float(e.y);
    float mx = xax + fmaf(ea, we2x, xr2x);
    float my = xay + fmaf(ea, we2y, xr2y);
    mx = fmaxf(mx, NEG_SLOPE * mx);
    my = fmaxf(my, NEG_SLOPE * my);
    float al = head16_sum(fmaf(my, aty, mx * atx));
    al = fminf(fmaxf(al, -60.f), 60.f);
    float pe = __expf(al);
    d += pe;
    ax = fmaf(pe, xax, ax);
    ay = fmaf(pe, xay, ay);
}

__global__ __launch_bounds__(256) void aggregate_kernel(
    float* __restrict__ h, const ushort* __restrict__ xl, const ushort* __restrict__ xr,
    const int* __restrict__ rowstart, const int2* __restrict__ csr,
    const float* __restrict__ We, const float* __restrict__ att, const float* __restrict__ bc,
    const float* __restrict__ ln_g, const float* __restrict__ ln_b,
    ushort* __restrict__ h_bf, float* __restrict__ h_out, int N_) {
    int wave = threadIdx.x >> 6;
    uint lane = threadIdx.x & 63;
    int n = blockIdx.x * 4 + wave;
    if (n >= N_) return;
    int c0 = lane * 2;
    int head = lane >> 4;
    const uint* xlw = (const uint*)xl;
    uint vr = *(const uint*)(xr + (size_t)n * 128 + c0);
    float xr2x = __uint_as_float(vr << 16);
    float xr2y = __uint_as_float(vr & 0xffff0000u);
    float2 we2 = *(const float2*)(We + c0);
    float2 at2 = *(const float2*)(att + head * 32 + (c0 & 31));
    int rs = rowstart[n], re = rowstart[n + 1];
    float d0 = 0.f, ax0 = 0.f, ay0 = 0.f;
    float d1 = 0.f, ax1 = 0.f, ay1 = 0.f;
    float d2 = 0.f, ax2 = 0.f, ay2 = 0.f;
    float d3 = 0.f, ax3 = 0.f, ay3 = 0.f;
    int p = rs;
    for (; p + 4 <= re; p += 4) {
        edge_step(xlw, csr, p,     lane, we2.x, we2.y, xr2x, xr2y, at2.x, at2.y, d0, ax0, ay0);
        edge_step(xlw, csr, p + 1, lane, we2.x, we2.y, xr2x, xr2y, at2.x, at2.y, d1, ax1, ay1);
        edge_step(xlw, csr, p + 2, lane, we2.x, we2.y, xr2x, xr2y, at2.x, at2.y, d2, ax2, ay2);
        edge_step(xlw, csr, p + 3, lane, we2.x, we2.y, xr2x, xr2y, at2.x, at2.y, d3, ax3, ay3);
    }
    for (; p < re; ++p)
        edge_step(xlw, csr, p, lane, we2.x, we2.y, xr2x, xr2y, at2.x, at2.y, d0, ax0, ay0);
    float den = (d0 + d1) + (d2 + d3);
    float accx = (ax0 + ax1) + (ax2 + ax3);
    float accy = (ay0 + ay1) + (ay2 + ay3);
    float inv = 1.f / den;
    float2 bc2 = *(const float2*)(bc + c0);
    float ox = accx * inv + bc2.x;
    float oy = accy * inv + bc2.y;
    ox = ox > 0.f ? ox : (__expf(ox) - 1.f);  // elu
    oy = oy > 0.f ? oy : (__expf(oy) - 1.f);
    float2 h2 = *(const float2*)(h + (size_t)n * 128 + c0);
    float tx = h2.x + ox, ty = h2.y + oy;
    // one-pass LN: reduce sum and sumsq together
    float s1v = tx + ty;
    float s2v = tx * tx + ty * ty;
#pragma unroll
    for (int m = 1; m < 64; m <<= 1) {
        s1v += __shfl_xor(s1v, m);
        s2v += __shfl_xor(s2v, m);
    }
    float mu = s1v * (1.f / 128.f);
    float var = s2v * (1.f / 128.f) - mu * mu;
    float rstd = rsqrtf(var + LN_EPS);
    float2 g2 = *(const float2*)(ln_g + c0);
    float2 b2 = *(const float2*)(ln_b + c0);
    float2 hn;
    hn.x = (tx - mu) * rstd * g2.x + b2.x;
    hn.y = (ty - mu) * rstd * g2.y + b2.y;
    *(float2*)(h + (size_t)n * 128 + c0) = hn;
    uint packed = (uint)f2bf(hn.x) | ((uint)f2bf(hn.y) << 16);
    *(uint*)(h_bf + (size_t)n * 128 + c0) = packed;
    if (h_out) *(float2*)(h_out + (size_t)n * 128 + c0) = hn;
}

// ---------------------------------------------------------------- outputs

__global__ __launch_bounds__(256) void batch_kernel(
    const float* __restrict__ h, const int* __restrict__ batch,
    float* __restrict__ gsum, float* __restrict__ gcnt, int N_, int chunk) {
    int wave_id = (blockIdx.x * 256 + threadIdx.x) >> 6;
    int lane = threadIdx.x & 63;
    int w0 = wave_id * chunk;
    if (w0 >= N_) return;
    int w1 = w0 + chunk; if (w1 > N_) w1 = N_;
    int c0 = lane * 2;
    int cur_b = batch[w0];
    float accx = 0.f, accy = 0.f, cntf = 0.f;
    for (int n = w0; n < w1; ++n) {
        float2 h2 = *(const float2*)(h + (size_t)n * 128 + c0);
        int b = batch[n];
        if (b != cur_b) {
            atomicAdd(&gsum[cur_b * 128 + c0], accx);
            atomicAdd(&gsum[cur_b * 128 + c0 + 1], accy);
            if (lane == 0) atomicAdd(gcnt + cur_b, cntf);
            accx = accy = cntf = 0.f;
            cur_b = b;
        }
        accx += h2.x; accy += h2.y; cntf += 1.f;
    }
    atomicAdd(&gsum[cur_b * 128 + c0], accx);
    atomicAdd(&gsum[cur_b * 128 + c0 + 1], accy);
    if (lane == 0) atomicAdd(gcnt + cur_b, cntf);
}

__global__ void graph_kernel(const float* __restrict__ gsum, const float* __restrict__ gcnt,
                             const float* __restrict__ Wg1, const float* __restrict__ bg1,
                             const float* __restrict__ Wg2, const float* __restrict__ bg2,
                             float* __restrict__ graph_emb) {
    __shared__ float gm[8 * 128];
    __shared__ float t1[8 * 128];
    int t = threadIdx.x;
    for (int i = t; i < 1024; i += 256) {
        int b = i >> 7;
        float c = gcnt[b];
        c = c > 1.f ? c : 1.f;
        gm[i] = gsum[i] / c;
    }
    __syncthreads();
    for (int i = t; i < 1024; i += 256) {
        int r = i >> 7, j = i & 127;
        float acc = bg1[j];
        for (int k = 0; k < 128; ++k) acc += gm[r * 128 + k] * Wg1[k * 128 + j];
        t1[i] = acc > 0.f ? acc : (__expf(acc) - 1.f);
    }
    __syncthreads();
    for (int i = t; i < 512; i += 256) {
        int r = i >> 6, j = i & 63;
        float acc = bg2[j];
        for (int k = 0; k < 128; ++k) acc += t1[r * 128 + k] * Wg2[k * 64 + j];
        graph_emb[r * 64 + j] = acc;
    }
}

// ---------------------------------------------------------------- launch

extern "C" void kernel_launch(void* const* d_in, const int* in_sizes, int n_in,
                              void* d_out, int out_size, void* d_ws, size_t ws_size,
                              hipStream_t stream) {
    const float* x         = (const float*)d_in[0];
    const int*   edge_index= (const int*)d_in[1];
    const float* edge_attr = (const float*)d_in[2];
    const int*   batch     = (const int*)d_in[3];
    const float* W_in      = (const float*)d_in[4];
    const float* b_in      = (const float*)d_in[5];
    const float* Wl        = (const float*)d_in[6];
    const float* bl        = (const float*)d_in[7];
    const float* Wr        = (const float*)d_in[8];
    const float* br        = (const float*)d_in[9];
    const float* We        = (const float*)d_in[10];
    const float* att       = (const float*)d_in[11];
    const float* bc        = (const float*)d_in[12];
    const float* ln_g      = (const float*)d_in[13];
    const float* ln_b      = (const float*)d_in[14];
    const float* Wn        = (const float*)d_in[15];
    const float* bn        = (const float*)d_in[16];
    const float* Wg1       = (const float*)d_in[17];
    const float* bg1       = (const float*)d_in[18];
    const float* Wg2       = (const float*)d_in[19];
    const float* bg2       = (const float*)d_in[20];

    const int N_ = in_sizes[3];   // batch is (N,)
    const int E_ = in_sizes[2];   // edge_attr is (E,1)

    const int* src0 = edge_index;
    const int* dst0 = edge_index + E_;

    float* ws = (float*)d_ws;
    float* h      = ws;                              // N*128 f32
    float* gsum   = h + (size_t)N_ * 128;            // 1024
    float* gcnt   = gsum + 1024;                     // 16 (8 used)
    int* cnt      = (int*)(gcnt + 16);               // N   (memset with gsum/gcnt)
    int* rowstart = cnt + N_;                        // N+2
    int* rank     = rowstart + N_ + 2;               // E
    int* blocksum = rank + E_;                       // 1024
    int* blockbase= blocksum + 1024;                 // 1024
    int2* csr     = (int2*)(blockbase + 1024);       // E+N (8B aligned: offset even)
    ushort* h_bf  = (ushort*)(csr + (size_t)(E_ + N_));   // N*128
    ushort* x_bf  = h_bf + (size_t)N_ * 128;              // N*32
    ushort* xl_bf = x_bf + (size_t)N_ * 32;               // N*128
    ushort* xr_bf = xl_bf + (size_t)N_ * 128;             // N*128
    ushort* wpack = xr_bf + (size_t)N_ * 128;             // 110592

    float* out_f     = (float*)d_out;
    float* node_emb  = out_f;                               // N*64
    float* graph_emb = out_f + (size_t)N_ * 64;             // 8*64
    float* h_out     = out_f + (size_t)N_ * 64 + 8 * 64;    // N*128

    // gsum, gcnt, cnt contiguous -> one memset
    hipMemsetAsync(gsum, 0, (1024 + 16 + (size_t)N_) * sizeof(float), stream);

    int nx4 = N_ * 8;  // x float4 count
    pack_cvt_kernel<<<(110592 + nx4 + 255) / 256, 256, 0, stream>>>(
        Wl, Wr, W_in, Wn, x, wpack, x_bf, nx4);
    count_kernel<<<(E_ + 255) / 256, 256, 0, stream>>>(dst0, cnt, rank, E_);

    int nb = (N_ + 1023) / 1024;  // <= 1024
    scan1_kernel<<<nb, 256, 0, stream>>>(cnt, blocksum, N_);
    scan2_kernel<<<1, 1024, 0, stream>>>(blocksum, blockbase, nb, rowstart, N_);
    scan3_kernel<<<nb, 256, 0, stream>>>(cnt, blockbase, rowstart, N_);

    scatter_kernel<<<(E_ + 255) / 256, 256, 0, stream>>>(src0, dst0, edge_attr, rank,
                                                         rowstart, csr, E_);
    selfloop_kernel<<<(N_ + 255) / 256, 256, 0, stream>>>(rowstart, csr, N_);

    mfma_inproj<<<(N_ + 63) / 64, 256, 0, stream>>>(x_bf, wpack + 98304, b_in, h, h_bf, N_);

    for (int l = 0; l < 3; ++l) {
        mfma_proj<<<(N_ + 127) / 128, 256, 0, stream>>>(
            h_bf, wpack + l * 16384, wpack + (3 + l) * 16384,
            bl + l * 128, br + l * 128, xl_bf, xr_bf, N_);
        aggregate_kernel<<<(N_ + 3) / 4, 256, 0, stream>>>(
            h, xl_bf, xr_bf, rowstart, csr, We + l * 128, att + l * 128,
            bc + l * 128, ln_g + l * 128, ln_b + l * 128,
            h_bf, (l == 2) ? h_out : (float*)nullptr, N_);
    }

    mfma_nodeemb<<<(N_ + 63) / 64, 256, 0, stream>>>(h_bf, wpack + 102400, bn, node_emb, N_);
    {
        int total_waves = 2048;
        int chunk = (N_ + total_waves - 1) / total_waves;
        batch_kernel<<<total_waves / 4, 256, 0, stream>>>(h, batch, gsum, gcnt, N_, chunk);
    }
    graph_kernel<<<1, 256, 0, stream>>>(gsum, gcnt, Wg1, bg1, Wg2, bg2, graph_emb);
}